// Round 7
// baseline (672.855 us; speedup 1.0000x reference)
//
#include <hip/hip_runtime.h>

// lstm_seq2seq fused persistent kernel for MI355X (gfx950), R15.
// = R14 structure (256 WGs x 512 thr x 64 rows, 1 WG/CU; A=weights streamed
// from L2 wave-contiguous; B=h in LDS double-buffer; c-state in regs;
// decoder feedback folded into weights; augmented K carries x and bias via
// "1" column; log2e folded into weight rows; kt=0 literal-zero C;
// PassA/E0/PassB/E1 interleave; merged-rcp EW) ported from
// mfma_f32_16x16x32_f16 to mfma_f32_32x32x16_f16:
//   - 32x32 MFMA rate is ~2495 TF vs ~2100 for 16x16 (m119): M-wall
//     11.2k -> ~8.8k cyc/step/SIMD (-21%), instruction count halves
//     (576 -> 272 issues/SIMD/step -> less VALU issue contention).
//   - K shrinks 288 -> 272 (K-tile 16: 256 h + x(2) + bias-one + pad).
//   - Per wave: 4 gate-tiles x 2 batch-tiles of 32x32, acc floatx16[4][2]
//     (same 128 f32 total; per-pass live 64 as in R14).
//   - C/D layout col=lane&31, row=(reg&3)+8*(reg>>2)+4*(lane>>5): packing
//     gates at rows g*8+cr puts all 4 gates of a cell in one lane
//     (reg=4g+m <-> cell m+4*hi) -> EW stays lane-local.
//   - decoder reduce: cells now spread only across lane-halves -> single
//     shfl_xor(32) instead of 16+32.
// A-load path stays plain global half8 loads (R9/R13: any perturbation
// there costs ~20% schedule quality).

#define SEQ  20
#define TLEN 30
#define LOG2E  1.442695041f
#define LOG2E2 2.885390082f

typedef _Float16 half8    __attribute__((ext_vector_type(8)));
typedef _Float16 half4    __attribute__((ext_vector_type(4)));
typedef float    floatx16 __attribute__((ext_vector_type(16)));

// Packed weights, 32x32x16 fragments. Gate row n (0..1023), k (0..271):
//   g=n>>8 (gate), c=n&255 (cell), w=c>>5, gt=(c>>3)&3, cr=c&7,
//   rr=g*8+cr (row in 32-row fragment), kt=k>>4, hi=(k>>3)&1, j=k&7
//   dst = (w*68 + kt*4 + gt)*512 + (hi*32 + rr)*8 + j
// => per (wave,kt): 4 contiguous 1KB A-fragments; lane l reads halves
//    [l*8, l*8+8) of each fragment (row=l&31, k=8*(l>>5)+j).
__device__ _Float16 g_w_enc[1024 * 272];
__device__ _Float16 g_w_dec0[1024 * 272];
__device__ _Float16 g_w_deff[1024 * 272];
__device__ _Float16 g_wout[512];           // W_out [2][256] f16 (unscaled)

__global__ void prep_kernel(const float* __restrict__ W_emb,
                            const float* __restrict__ b_emb,
                            const float* __restrict__ W_ih_enc,
                            const float* __restrict__ W_hh_enc,
                            const float* __restrict__ b_enc,
                            const float* __restrict__ W_ih_dec,
                            const float* __restrict__ W_hh_dec,
                            const float* __restrict__ b_dec,
                            const float* __restrict__ W_out,
                            const float* __restrict__ b_out) {
    int gid = blockIdx.x * blockDim.x + threadIdx.x;
    int stride = gridDim.x * blockDim.x;
    for (int s = gid; s < 1024 * 272; s += stride) {
        int n = s / 272, k = s - n * 272;
        int g = n >> 8, c = n & 255;
        int w = c >> 5, gt = (c >> 3) & 3, cr = c & 7;
        int rr = g * 8 + cr;
        int kt = k >> 4, hi = (k >> 3) & 1, j = k & 7;
        int dst = (w * 68 + kt * 4 + gt) * 512 + (hi * 32 + rr) * 8 + j;
        float sc = (g == 2) ? LOG2E2 : LOG2E;   // exp2-folded row scale
        float fe = 0.f, fd = 0.f, ff = 0.f;
        if (k < 256) {
            fe = W_hh_enc[n * 256 + k];
            fd = W_hh_dec[n * 256 + k];
            ff = fd + W_ih_dec[2 * n] * W_out[k]
                    + W_ih_dec[2 * n + 1] * W_out[256 + k];
        } else {
            int kp = k - 256;
            if (kp < 2) {
                fd = W_ih_dec[2 * n + kp];
                const float* wr = &W_ih_enc[n * 64];
                for (int e = 0; e < 64; e++) fe = fmaf(wr[e], W_emb[2 * e + kp], fe);
            } else if (kp == 2) {
                fd = b_dec[n];
                ff = b_dec[n] + W_ih_dec[2 * n] * b_out[0]
                              + W_ih_dec[2 * n + 1] * b_out[1];
                fe = b_enc[n];
                const float* wr = &W_ih_enc[n * 64];
                for (int e = 0; e < 64; e++) fe = fmaf(wr[e], b_emb[e], fe);
            }
        }
        g_w_enc[dst]  = (_Float16)(fe * sc);
        g_w_dec0[dst] = (_Float16)(fd * sc);
        g_w_deff[dst] = (_Float16)(ff * sc);
    }
    if (gid < 512) g_wout[gid] = (_Float16)W_out[gid];
}

__global__ __launch_bounds__(512, 2) void lstm_fused(
        const float* __restrict__ x_input,    // [20][16384][2]
        const float* __restrict__ b_out,      // [2]
        float* __restrict__ out)              // [30][16384][2]
{
    // h_pack halves layout: idx = (blk*64 + col)*8 + off, blk = k>>3 (0..33),
    // col = batch row in WG (0..63), off = k&7. K=272: blk 0..31 = h cells,
    // blk 32 off 0,1 = x, off 2 = "1" (bias), rest zero.
    __shared__ __align__(16) _Float16 h_pack[2][17408];        // 69632 B
    __shared__ __align__(16) float    partial_lds[2][8 * 132]; // 8448 B

    const int tid = threadIdx.x;
    const int w   = tid >> 6;
    const int L   = tid & 63;
    const int lc  = L & 31;
    const int hi  = L >> 5;
    const long row0 = (long)blockIdx.x * 64;

    // ---- init ----
    {
        int* hz = (int*)&h_pack[0][0];
        for (int idx = tid; idx < 17408; idx += 512) hz[idx] = 0;  // both bufs
    }
    __syncthreads();
    if (tid < 128) {   // "1" column (k=258), both buffers, never overwritten
        int buf = tid >> 6, b = tid & 63;
        h_pack[buf][(2048 + b) * 8 + 2] = (_Float16)1.f;
    }
    if (tid < 128) {   // x(0) into buf0 (k=256,257)
        int b = tid >> 1, jj = tid & 1;
        h_pack[0][(2048 + b) * 8 + jj] =
            (_Float16)x_input[(row0 + b) * 2 + jj];
    }

    const float bo = b_out[tid & 1];
    const int aoff = L * 8;                 // A fragment lane offset
    const int boff = hi * 512 + lc * 8;     // B fragment lane offset
    const _Float16* __restrict__ wenc_w  = &g_w_enc[w * 34816];
    const _Float16* __restrict__ wdec0_w = &g_w_dec0[w * 34816];
    const _Float16* __restrict__ wdeff_w = &g_w_deff[w * 34816];

    _Float16 wo[2][4][4];   // [jj][gt][m] for cell w*32 + gt*8 + 4*hi + m
#pragma unroll
    for (int jj = 0; jj < 2; jj++)
#pragma unroll
        for (int gt = 0; gt < 4; gt++)
#pragma unroll
            for (int m = 0; m < 4; m++)
                wo[jj][gt][m] = g_wout[jj * 256 + w * 32 + gt * 8 + 4 * hi + m];

    floatx16 acc[4][2];     // [gt][bt]; per-pass live = 2x2 tiles
    float    c_st[4][2][4]; // [gt][bt][m]
#pragma unroll
    for (int gt = 0; gt < 4; gt++)
#pragma unroll
        for (int bt = 0; bt < 2; bt++)
#pragma unroll
            for (int m = 0; m < 4; m++) c_st[gt][bt][m] = 0.f;

    __syncthreads();

    int cur = 0;
#pragma unroll 1
    for (int t = 0; t < SEQ + TLEN; t++) {
        const _Float16* __restrict__ Wb =
            (t < SEQ) ? wenc_w : (t == SEQ) ? wdec0_w : wdeff_w;
        const _Float16* __restrict__ hp = h_pack[cur];
        _Float16* __restrict__ hn = h_pack[cur ^ 1];
        const bool dec = (t >= SEQ);

        float xval = 0.f;
        if (t < SEQ && tid < 128) {
            int srct = (t + 1 < SEQ) ? t + 1 : SEQ - 1;
            xval = x_input[(long)srct * 32768 + (row0 + (tid >> 1)) * 2 + (tid & 1)];
        }

        float po[2][2];     // [bt][jj]
#pragma unroll
        for (int bt = 0; bt < 2; bt++) { po[bt][0] = 0.f; po[bt][1] = 0.f; }

        // ==== PassA: gate-tiles 0,1 ; all kt ====
#pragma unroll
        for (int kt = 0; kt < 17; kt++) {
            half8 B0 = *(const half8*)&hp[kt * 1024 + boff];
            half8 B1 = *(const half8*)&hp[kt * 1024 + 256 + boff];
#pragma unroll
            for (int gi = 0; gi < 2; gi++) {
                half8 Aw = *(const half8*)&Wb[(kt * 4 + gi) * 512 + aoff];
                if (kt == 0) {
                    acc[gi][0] = __builtin_amdgcn_mfma_f32_32x32x16_f16(
                        Aw, B0, (floatx16)(0.f), 0, 0, 0);
                    acc[gi][1] = __builtin_amdgcn_mfma_f32_32x32x16_f16(
                        Aw, B1, (floatx16)(0.f), 0, 0, 0);
                } else {
                    acc[gi][0] = __builtin_amdgcn_mfma_f32_32x32x16_f16(
                        Aw, B0, acc[gi][0], 0, 0, 0);
                    acc[gi][1] = __builtin_amdgcn_mfma_f32_32x32x16_f16(
                        Aw, B1, acc[gi][1], 0, 0, 0);
                }
            }
        }

        // ==== E0: EW for gate-tiles 0,1 (schedulable into PassB shadow) ====
#pragma unroll
        for (int gt = 0; gt < 2; gt++)
#pragma unroll
            for (int bt = 0; bt < 2; bt++) {
                half4 hv4;
                float hvf[4];
#pragma unroll
                for (int m = 0; m < 4; m++) {
                    float ai = acc[gt][bt][m];
                    float af = acc[gt][bt][4 + m];
                    float ag = acc[gt][bt][8 + m];
                    float ao = acc[gt][bt][12 + m];
                    float eI = __builtin_amdgcn_exp2f(-ai);
                    float eF = __builtin_amdgcn_exp2f(-af);
                    float eG = __builtin_amdgcn_exp2f(-ag);
                    float eO = __builtin_amdgcn_exp2f(-ao);
                    float a1 = 1.f + eI;
                    float a2 = 1.f + eG;
                    float a3 = 1.f + eF;
                    float t1 = a1 * a2;
                    float num = fmaf(c_st[gt][bt][m], t1, (1.f - eG) * a3);
                    float cn  = num * __builtin_amdgcn_rcpf(t1 * a3);
                    c_st[gt][bt][m] = cn;
                    float cnc = fmaxf(cn, -12.f);
                    float eC = __builtin_amdgcn_exp2f(-LOG2E2 * cnc);
                    float hv = (1.f - eC) *
                        __builtin_amdgcn_rcpf((1.f + eO) * (1.f + eC));
                    hvf[m] = hv;
                    hv4[m] = (_Float16)hv;
                }
                *(half4*)&hn[((w * 4 + gt) * 64 + bt * 32 + lc) * 8 + 4 * hi] = hv4;
                if (dec) {
#pragma unroll
                    for (int m = 0; m < 4; m++) {
                        po[bt][0] = fmaf(hvf[m], (float)wo[0][gt][m], po[bt][0]);
                        po[bt][1] = fmaf(hvf[m], (float)wo[1][gt][m], po[bt][1]);
                    }
                }
            }

        // ==== PassB: gate-tiles 2,3 ; all kt ====
#pragma unroll
        for (int kt = 0; kt < 17; kt++) {
            half8 B0 = *(const half8*)&hp[kt * 1024 + boff];
            half8 B1 = *(const half8*)&hp[kt * 1024 + 256 + boff];
#pragma unroll
            for (int gi = 2; gi < 4; gi++) {
                half8 Aw = *(const half8*)&Wb[(kt * 4 + gi) * 512 + aoff];
                if (kt == 0) {
                    acc[gi][0] = __builtin_amdgcn_mfma_f32_32x32x16_f16(
                        Aw, B0, (floatx16)(0.f), 0, 0, 0);
                    acc[gi][1] = __builtin_amdgcn_mfma_f32_32x32x16_f16(
                        Aw, B1, (floatx16)(0.f), 0, 0, 0);
                } else {
                    acc[gi][0] = __builtin_amdgcn_mfma_f32_32x32x16_f16(
                        Aw, B0, acc[gi][0], 0, 0, 0);
                    acc[gi][1] = __builtin_amdgcn_mfma_f32_32x32x16_f16(
                        Aw, B1, acc[gi][1], 0, 0, 0);
                }
            }
        }

        // ==== E1: EW for gate-tiles 2,3 ====
#pragma unroll
        for (int gt = 2; gt < 4; gt++)
#pragma unroll
            for (int bt = 0; bt < 2; bt++) {
                half4 hv4;
                float hvf[4];
#pragma unroll
                for (int m = 0; m < 4; m++) {
                    float ai = acc[gt][bt][m];
                    float af = acc[gt][bt][4 + m];
                    float ag = acc[gt][bt][8 + m];
                    float ao = acc[gt][bt][12 + m];
                    float eI = __builtin_amdgcn_exp2f(-ai);
                    float eF = __builtin_amdgcn_exp2f(-af);
                    float eG = __builtin_amdgcn_exp2f(-ag);
                    float eO = __builtin_amdgcn_exp2f(-ao);
                    float a1 = 1.f + eI;
                    float a2 = 1.f + eG;
                    float a3 = 1.f + eF;
                    float t1 = a1 * a2;
                    float num = fmaf(c_st[gt][bt][m], t1, (1.f - eG) * a3);
                    float cn  = num * __builtin_amdgcn_rcpf(t1 * a3);
                    c_st[gt][bt][m] = cn;
                    float cnc = fmaxf(cn, -12.f);
                    float eC = __builtin_amdgcn_exp2f(-LOG2E2 * cnc);
                    float hv = (1.f - eC) *
                        __builtin_amdgcn_rcpf((1.f + eO) * (1.f + eC));
                    hvf[m] = hv;
                    hv4[m] = (_Float16)hv;
                }
                *(half4*)&hn[((w * 4 + gt) * 64 + bt * 32 + lc) * 8 + 4 * hi] = hv4;
                if (dec) {
#pragma unroll
                    for (int m = 0; m < 4; m++) {
                        po[bt][0] = fmaf(hvf[m], (float)wo[0][gt][m], po[bt][0]);
                        po[bt][1] = fmaf(hvf[m], (float)wo[1][gt][m], po[bt][1]);
                    }
                }
            }

        if (dec) {
#pragma unroll
            for (int bt = 0; bt < 2; bt++)
#pragma unroll
                for (int jj = 0; jj < 2; jj++) {
                    float s = po[bt][jj];
                    s += __shfl_xor(s, 32);   // cells spread only across hi
                    po[bt][jj] = s;
                }
            if (hi == 0) {
                float* pl = &partial_lds[t & 1][w * 132];
#pragma unroll
                for (int bt = 0; bt < 2; bt++) {
                    pl[bt * 32 + lc]      = po[bt][0];
                    pl[66 + bt * 32 + lc] = po[bt][1];
                }
            }
        }

        if (t < SEQ && tid < 128) {
            int b = tid >> 1, jj = tid & 1;
            hn[(2048 + b) * 8 + jj] = (_Float16)xval;
        }

        __syncthreads();   // hn + partials complete

        if (dec && tid < 128) {
            int m = tid >> 1, jj = tid & 1;
            const float* pl = &partial_lds[t & 1][jj * 66 + m];
            float s = bo;
#pragma unroll
            for (int w8 = 0; w8 < 8; w8++) s += pl[w8 * 132];
            out[(long)(t - SEQ) * 32768 + (row0 + m) * 2 + jj] = s;
        }

        cur ^= 1;
    }
}

extern "C" void kernel_launch(void* const* d_in, const int* in_sizes, int n_in,
                              void* d_out, int out_size, void* d_ws, size_t ws_size,
                              hipStream_t stream) {
    (void)in_sizes; (void)n_in; (void)d_ws; (void)ws_size; (void)out_size;
    const float* x      = (const float*)d_in[0];
    const float* W_emb  = (const float*)d_in[1];
    const float* b_emb  = (const float*)d_in[2];
    const float* W_ih_e = (const float*)d_in[3];
    const float* W_hh_e = (const float*)d_in[4];
    const float* b_enc  = (const float*)d_in[5];
    const float* W_ih_d = (const float*)d_in[6];
    const float* W_hh_d = (const float*)d_in[7];
    const float* b_dec  = (const float*)d_in[8];
    const float* W_out  = (const float*)d_in[9];
    const float* b_out  = (const float*)d_in[10];
    float* outp = (float*)d_out;

    prep_kernel<<<512, 256, 0, stream>>>(W_emb, b_emb, W_ih_e, W_hh_e, b_enc,
                                         W_ih_d, W_hh_d, b_dec, W_out, b_out);
    lstm_fused<<<256, 512, 0, stream>>>(x, b_out, outp);
}

// Round 8
// 645.791 us; speedup vs baseline: 1.0419x; 1.0419x over previous
//
#include <hip/hip_runtime.h>

// lstm_seq2seq fused persistent kernel for MI355X (gfx950), R16.
// = R14 (256 WGs x 512 thr x 64 rows, 1 WG/CU; A=weights streamed from L2
// wave-contiguous; B=h in LDS double-buffer; c-state in regs; decoder
// feedback folded into weights; K=288 augmented, "1" column carries bias;
// log2e folded into weight rows; kt=0 literal-zero C; merged-rcp EW;
// PassA/PassB split by i-halves) with ONE change:
//   - E0 (EW for cc=0 cells) is EXPLICITLY interleaved into PassB's kt-loop
//     as four nt-chunks placed after kt=1,3,5,7 (compile-time positions in
//     the unrolled loop). R14 relied on the post-unroll scheduler to sink
//     E0 into PassB's MFMA shadow across a ~700-instruction region; placing
//     the independent VALU chunks locally adjacent to PassB's MFMAs removes
//     the scheduling-window dependence (attn "sm-split" pattern).
// R15 (32x32x16 MFMA) reverted: faster MFMA pipe exposed the weight stream
// (demand 63 B/cyc/CU > per-CU L2 share ~50) and dropped chain ILP 16->4;
// stream-bound passes cost +130 us. The M-phase floor is min(MFMA pipe,
// weight stream); only byte reduction helps past it, not a faster pipe.

#define SEQ  20
#define TLEN 30
#define LOG2E  1.442695041f
#define LOG2E2 2.885390082f

typedef _Float16 half8   __attribute__((ext_vector_type(8)));
typedef _Float16 half4   __attribute__((ext_vector_type(4)));
typedef float    floatx4 __attribute__((ext_vector_type(4)));

// Packed weights. Gate row n (0..1023), k (0..287):
//   g=n>>8, c=(n>>4)&15, l16=n&15, w=c>>1, cc=c&1, i=cc*4+g,
//   kt=k>>5, q=(k>>3)&3, j=k&7
//   dst = ((w*9+kt)*8 + i)*512 + q*128 + l16*8 + j
// => per (wave,kt): 8 contiguous 1KB A-fragments (8KB block).
__device__ _Float16 g_w_enc[1024 * 288];
__device__ _Float16 g_w_dec0[1024 * 288];
__device__ _Float16 g_w_deff[1024 * 288];
__device__ _Float16 g_wout[512];           // W_out [2][256] f16 (unscaled)

__global__ void prep_kernel(const float* __restrict__ W_emb,
                            const float* __restrict__ b_emb,
                            const float* __restrict__ W_ih_enc,
                            const float* __restrict__ W_hh_enc,
                            const float* __restrict__ b_enc,
                            const float* __restrict__ W_ih_dec,
                            const float* __restrict__ W_hh_dec,
                            const float* __restrict__ b_dec,
                            const float* __restrict__ W_out,
                            const float* __restrict__ b_out) {
    int gid = blockIdx.x * blockDim.x + threadIdx.x;
    int stride = gridDim.x * blockDim.x;
    for (int s = gid; s < 1024 * 288; s += stride) {
        int n = s / 288, k = s - n * 288;
        int g = n >> 8, c = (n >> 4) & 15, l16 = n & 15;
        int w = c >> 1, cc = c & 1;
        int i = cc * 4 + g;
        int kt = k >> 5, q = (k >> 3) & 3, j = k & 7;
        int dst = ((w * 9 + kt) * 8 + i) * 512 + q * 128 + l16 * 8 + j;
        float sc = (g == 2) ? LOG2E2 : LOG2E;   // exp2-folded row scale
        float fe = 0.f, fd = 0.f, ff = 0.f;
        if (k < 256) {
            fe = W_hh_enc[n * 256 + k];
            fd = W_hh_dec[n * 256 + k];
            ff = fd + W_ih_dec[2 * n] * W_out[k]
                    + W_ih_dec[2 * n + 1] * W_out[256 + k];
        } else {
            int kp = k - 256;
            if (kp < 2) {
                fd = W_ih_dec[2 * n + kp];
                const float* wr = &W_ih_enc[n * 64];
                for (int e = 0; e < 64; e++) fe = fmaf(wr[e], W_emb[2 * e + kp], fe);
            } else if (kp == 2) {
                fd = b_dec[n];
                ff = b_dec[n] + W_ih_dec[2 * n] * b_out[0]
                              + W_ih_dec[2 * n + 1] * b_out[1];
                fe = b_enc[n];
                const float* wr = &W_ih_enc[n * 64];
                for (int e = 0; e < 64; e++) fe = fmaf(wr[e], b_emb[e], fe);
            }
        }
        g_w_enc[dst]  = (_Float16)(fe * sc);
        g_w_dec0[dst] = (_Float16)(fd * sc);
        g_w_deff[dst] = (_Float16)(ff * sc);
    }
    if (gid < 512) g_wout[gid] = (_Float16)W_out[gid];
}

__global__ __launch_bounds__(512, 2) void lstm_fused(
        const float* __restrict__ x_input,    // [20][16384][2]
        const float* __restrict__ b_out,      // [2]
        float* __restrict__ out)              // [30][16384][2]
{
    __shared__ __align__(16) _Float16 h_pack[2][18432];        // 73728 B
    __shared__ __align__(16) float    partial_lds[2][8 * 132]; // 8448 B

    const int tid = threadIdx.x;
    const int w   = tid >> 6;
    const int L   = tid & 63;
    const int l16 = L & 15;
    const int q   = L >> 4;
    const long row0 = (long)blockIdx.x * 64;

    // ---- init ----
    {
        int* hz = (int*)&h_pack[0][0];
        for (int idx = tid; idx < 18432; idx += 512) hz[idx] = 0;  // both bufs
    }
    __syncthreads();
    if (tid < 128) {   // "1" column, both buffers, never overwritten
        int buf = tid >> 6, b = tid & 63;
        h_pack[buf][((b >> 4) * 9 + 8) * 512 + (b & 15) * 8 + 2] = (_Float16)1.f;
    }
    if (tid < 128) {   // x(0) into buf0
        int b = tid >> 1, jj = tid & 1;
        h_pack[0][((b >> 4) * 9 + 8) * 512 + (b & 15) * 8 + jj] =
            (_Float16)x_input[(row0 + b) * 2 + jj];
    }

    const float bo = b_out[tid & 1];
    const int aoff = q * 128 + l16 * 8;
    const _Float16* __restrict__ wenc_w  = &g_w_enc[w * 36864];
    const _Float16* __restrict__ wdec0_w = &g_w_dec0[w * 36864];
    const _Float16* __restrict__ wdeff_w = &g_w_deff[w * 36864];

    _Float16 wo[2][2][4];   // [jj][cc][r] for cells 32w+16cc+4q+r
#pragma unroll
    for (int jj = 0; jj < 2; jj++)
#pragma unroll
        for (int cc = 0; cc < 2; cc++)
#pragma unroll
            for (int r = 0; r < 4; r++)
                wo[jj][cc][r] = g_wout[jj * 256 + 32 * w + 16 * cc + 4 * q + r];

    floatx4 acc[8][4];
    float   c_st[4][2][4];
#pragma unroll
    for (int nt = 0; nt < 4; nt++)
#pragma unroll
        for (int cc = 0; cc < 2; cc++)
#pragma unroll
            for (int r = 0; r < 4; r++) c_st[nt][cc][r] = 0.f;

    __syncthreads();

    int cur = 0;
#pragma unroll 1
    for (int t = 0; t < SEQ + TLEN; t++) {
        const _Float16* __restrict__ Wb =
            (t < SEQ) ? wenc_w : (t == SEQ) ? wdec0_w : wdeff_w;
        const _Float16* __restrict__ hp = h_pack[cur];
        _Float16* __restrict__ hn = h_pack[cur ^ 1];
        const bool dec = (t >= SEQ);

        float xval = 0.f;
        if (t < SEQ && tid < 128) {
            int srct = (t + 1 < SEQ) ? t + 1 : SEQ - 1;
            xval = x_input[(long)srct * 32768 + (row0 + (tid >> 1)) * 2 + (tid & 1)];
        }

        float po[4][2];
#pragma unroll
        for (int nt = 0; nt < 4; nt++) { po[nt][0] = 0.f; po[nt][1] = 0.f; }

        // EW chunk for one (cc, nt): merged-rcp LSTM elementwise, h-store,
        // decoder po accumulation. Called with compile-time cc/nt.
        auto ew_chunk = [&](int cc, int nt) {
            half4 hv4;
            float hvf[4];
#pragma unroll
            for (int r = 0; r < 4; r++) {
                float ai = acc[cc * 4 + 0][nt][r];
                float af = acc[cc * 4 + 1][nt][r];
                float ag = acc[cc * 4 + 2][nt][r];
                float ao = acc[cc * 4 + 3][nt][r];
                float eI = __builtin_amdgcn_exp2f(-ai);
                float eF = __builtin_amdgcn_exp2f(-af);
                float eG = __builtin_amdgcn_exp2f(-ag);
                float eO = __builtin_amdgcn_exp2f(-ao);
                float a1 = 1.f + eI;
                float a2 = 1.f + eG;
                float a3 = 1.f + eF;
                float t1 = a1 * a2;
                float num = fmaf(c_st[nt][cc][r], t1, (1.f - eG) * a3);
                float cn  = num * __builtin_amdgcn_rcpf(t1 * a3);
                c_st[nt][cc][r] = cn;
                float cnc = fmaxf(cn, -12.f);   // upper clamp unnecessary
                float eC = __builtin_amdgcn_exp2f(-LOG2E2 * cnc);
                float hv = (1.f - eC) *
                    __builtin_amdgcn_rcpf((1.f + eO) * (1.f + eC));
                hvf[r] = hv;
                hv4[r] = (_Float16)hv;
            }
            *(half4*)&hn[(nt * 9 + w) * 512 + (2 * cc + (q >> 1)) * 128 +
                         l16 * 8 + 4 * (q & 1)] = hv4;
            if (dec) {
#pragma unroll
                for (int r = 0; r < 4; r++) {
                    po[nt][0] = fmaf(hvf[r], (float)wo[0][cc][r], po[nt][0]);
                    po[nt][1] = fmaf(hvf[r], (float)wo[1][cc][r], po[nt][1]);
                }
            }
        };

        // ==== PassA: gates for cc=0 cells (i=0..3), all kt ====
#pragma unroll
        for (int kt = 0; kt < 9; kt++) {
            half8 B[4];
#pragma unroll
            for (int nt = 0; nt < 4; nt++)
                B[nt] = *(const half8*)&hp[(nt * 9 + kt) * 512 + aoff];
#pragma unroll
            for (int i = 0; i < 4; i++) {
                half8 Aw = *(const half8*)&Wb[(kt * 8 + i) * 512 + aoff];
                if (kt == 0) {
#pragma unroll
                    for (int nt = 0; nt < 4; nt++)
                        acc[i][nt] = __builtin_amdgcn_mfma_f32_16x16x32_f16(
                            Aw, B[nt], (floatx4)(0.f), 0, 0, 0);
                } else {
#pragma unroll
                    for (int nt = 0; nt < 4; nt++)
                        acc[i][nt] = __builtin_amdgcn_mfma_f32_16x16x32_f16(
                            Aw, B[nt], acc[i][nt], 0, 0, 0);
                }
            }
        }

        // ==== PassB: gates for cc=1 cells (i=4..7), all kt, with E0's four
        // nt-chunks interleaved at kt=1,3,5,7 (independent VALU work placed
        // locally in the MFMA shadow) ====
#pragma unroll
        for (int kt = 0; kt < 9; kt++) {
            half8 B[4];
#pragma unroll
            for (int nt = 0; nt < 4; nt++)
                B[nt] = *(const half8*)&hp[(nt * 9 + kt) * 512 + aoff];
#pragma unroll
            for (int i = 4; i < 8; i++) {
                half8 Aw = *(const half8*)&Wb[(kt * 8 + i) * 512 + aoff];
                if (kt == 0) {
#pragma unroll
                    for (int nt = 0; nt < 4; nt++)
                        acc[i][nt] = __builtin_amdgcn_mfma_f32_16x16x32_f16(
                            Aw, B[nt], (floatx4)(0.f), 0, 0, 0);
                } else {
#pragma unroll
                    for (int nt = 0; nt < 4; nt++)
                        acc[i][nt] = __builtin_amdgcn_mfma_f32_16x16x32_f16(
                            Aw, B[nt], acc[i][nt], 0, 0, 0);
                }
            }
            if (kt == 1) ew_chunk(0, 0);
            if (kt == 3) ew_chunk(0, 1);
            if (kt == 5) ew_chunk(0, 2);
            if (kt == 7) ew_chunk(0, 3);
        }

        // ==== E1: EW for cc=1 cells (acc[4..7]; exposed tail) ====
        ew_chunk(1, 0);
        ew_chunk(1, 1);
        ew_chunk(1, 2);
        ew_chunk(1, 3);

        if (dec) {
#pragma unroll
            for (int nt = 0; nt < 4; nt++)
#pragma unroll
                for (int jj = 0; jj < 2; jj++) {
                    float s = po[nt][jj];
                    s += __shfl_xor(s, 16);
                    s += __shfl_xor(s, 32);
                    po[nt][jj] = s;
                }
            if (q == 0) {
                float* pl = &partial_lds[t & 1][w * 132];
#pragma unroll
                for (int nt = 0; nt < 4; nt++) {
                    pl[nt * 16 + l16]      = po[nt][0];
                    pl[66 + nt * 16 + l16] = po[nt][1];
                }
            }
        }

        if (t < SEQ && tid < 128) {
            int b = tid >> 1, jj = tid & 1;
            hn[((b >> 4) * 9 + 8) * 512 + (b & 15) * 8 + jj] = (_Float16)xval;
        }

        __syncthreads();   // hn + partials complete

        if (dec && tid < 128) {
            int m = tid >> 1, jj = tid & 1;
            const float* pl = &partial_lds[t & 1][jj * 66 + m];
            float s = bo;
#pragma unroll
            for (int w8 = 0; w8 < 8; w8++) s += pl[w8 * 132];
            out[(long)(t - SEQ) * 32768 + (row0 + m) * 2 + jj] = s;
        }

        cur ^= 1;
    }
}

extern "C" void kernel_launch(void* const* d_in, const int* in_sizes, int n_in,
                              void* d_out, int out_size, void* d_ws, size_t ws_size,
                              hipStream_t stream) {
    (void)in_sizes; (void)n_in; (void)d_ws; (void)ws_size; (void)out_size;
    const float* x      = (const float*)d_in[0];
    const float* W_emb  = (const float*)d_in[1];
    const float* b_emb  = (const float*)d_in[2];
    const float* W_ih_e = (const float*)d_in[3];
    const float* W_hh_e = (const float*)d_in[4];
    const float* b_enc  = (const float*)d_in[5];
    const float* W_ih_d = (const float*)d_in[6];
    const float* W_hh_d = (const float*)d_in[7];
    const float* b_dec  = (const float*)d_in[8];
    const float* W_out  = (const float*)d_in[9];
    const float* b_out  = (const float*)d_in[10];
    float* outp = (float*)d_out;

    prep_kernel<<<512, 256, 0, stream>>>(W_emb, b_emb, W_ih_e, W_hh_e, b_enc,
                                         W_ih_d, W_hh_d, b_dec, W_out, b_out);
    lstm_fused<<<256, 512, 0, stream>>>(x, b_out, outp);
}

// Round 9
// 589.226 us; speedup vs baseline: 1.1419x; 1.0960x over previous
//
#include <hip/hip_runtime.h>

// lstm_seq2seq fused persistent kernel for MI355X (gfx950), R17 = R14 exact.
// (256 WGs x 512 thr x 64 rows, 1 WG/CU; A=weights streamed from L2
// wave-contiguous; B=h in LDS double-buffer; c-state in regs; decoder
// feedback folded into weights; K=288 augmented, "1" column carries bias;
// log2e folded into weight rows; kt=0 literal-zero C; merged-rcp EW;
// PassA(i=0..3) ; E0(cc=0) ; PassB(i=4..7) ; E1(cc=1) step structure --
// E0 sinks into PassB's MFMA shadow via the post-unroll scheduler).
//
// Session ledger (hot-dispatch us): R8/R11 590 -> R14 552 (PassA/E0/PassB/E1
// split: +MfmaUtil 38->41.8, VGPR 128->112). Failed deltas off R14:
//   R15 32x32x16 MFMA   -> 681 (faster MFMA pipe exposed weight stream;
//                               chain ILP 16->4; M-phase went stream-bound)
//   R16 manual EW-in-kt-loop interleave -> 669 (live ranges -> VGPR cap,
//                               ds_writes broke the B ds_read pipeline)
//   R12 2 WG/CU         -> 921 (weight stream per CU doubles; spills)
//   R9/R13 A-tile LDS/glds staging -> 666/721 (any touch of the A-load
//                               path costs ~8-20% schedule quality)
// Structure is compiler-schedule-fragile: keep passes as clean unrolled
// blobs, EW as separate contiguous blocks, A-loads as plain global half8.

#define SEQ  20
#define TLEN 30
#define LOG2E  1.442695041f
#define LOG2E2 2.885390082f

typedef _Float16 half8   __attribute__((ext_vector_type(8)));
typedef _Float16 half4   __attribute__((ext_vector_type(4)));
typedef float    floatx4 __attribute__((ext_vector_type(4)));

// Packed weights. Gate row n (0..1023), k (0..287):
//   g=n>>8, c=(n>>4)&15, l16=n&15, w=c>>1, cc=c&1, i=cc*4+g,
//   kt=k>>5, q=(k>>3)&3, j=k&7
//   dst = ((w*9+kt)*8 + i)*512 + q*128 + l16*8 + j
// => per (wave,kt): 8 contiguous 1KB A-fragments (8KB block).
__device__ _Float16 g_w_enc[1024 * 288];
__device__ _Float16 g_w_dec0[1024 * 288];
__device__ _Float16 g_w_deff[1024 * 288];
__device__ _Float16 g_wout[512];           // W_out [2][256] f16 (unscaled)

__global__ void prep_kernel(const float* __restrict__ W_emb,
                            const float* __restrict__ b_emb,
                            const float* __restrict__ W_ih_enc,
                            const float* __restrict__ W_hh_enc,
                            const float* __restrict__ b_enc,
                            const float* __restrict__ W_ih_dec,
                            const float* __restrict__ W_hh_dec,
                            const float* __restrict__ b_dec,
                            const float* __restrict__ W_out,
                            const float* __restrict__ b_out) {
    int gid = blockIdx.x * blockDim.x + threadIdx.x;
    int stride = gridDim.x * blockDim.x;
    for (int s = gid; s < 1024 * 288; s += stride) {
        int n = s / 288, k = s - n * 288;
        int g = n >> 8, c = (n >> 4) & 15, l16 = n & 15;
        int w = c >> 1, cc = c & 1;
        int i = cc * 4 + g;
        int kt = k >> 5, q = (k >> 3) & 3, j = k & 7;
        int dst = ((w * 9 + kt) * 8 + i) * 512 + q * 128 + l16 * 8 + j;
        float sc = (g == 2) ? LOG2E2 : LOG2E;   // exp2-folded row scale
        float fe = 0.f, fd = 0.f, ff = 0.f;
        if (k < 256) {
            fe = W_hh_enc[n * 256 + k];
            fd = W_hh_dec[n * 256 + k];
            ff = fd + W_ih_dec[2 * n] * W_out[k]
                    + W_ih_dec[2 * n + 1] * W_out[256 + k];
        } else {
            int kp = k - 256;
            if (kp < 2) {
                fd = W_ih_dec[2 * n + kp];
                const float* wr = &W_ih_enc[n * 64];
                for (int e = 0; e < 64; e++) fe = fmaf(wr[e], W_emb[2 * e + kp], fe);
            } else if (kp == 2) {
                fd = b_dec[n];
                ff = b_dec[n] + W_ih_dec[2 * n] * b_out[0]
                              + W_ih_dec[2 * n + 1] * b_out[1];
                fe = b_enc[n];
                const float* wr = &W_ih_enc[n * 64];
                for (int e = 0; e < 64; e++) fe = fmaf(wr[e], b_emb[e], fe);
            }
        }
        g_w_enc[dst]  = (_Float16)(fe * sc);
        g_w_dec0[dst] = (_Float16)(fd * sc);
        g_w_deff[dst] = (_Float16)(ff * sc);
    }
    if (gid < 512) g_wout[gid] = (_Float16)W_out[gid];
}

__global__ __launch_bounds__(512, 2) void lstm_fused(
        const float* __restrict__ x_input,    // [20][16384][2]
        const float* __restrict__ b_out,      // [2]
        float* __restrict__ out)              // [30][16384][2]
{
    __shared__ __align__(16) _Float16 h_pack[2][18432];        // 73728 B
    __shared__ __align__(16) float    partial_lds[2][8 * 132]; // 8448 B

    const int tid = threadIdx.x;
    const int w   = tid >> 6;
    const int L   = tid & 63;
    const int l16 = L & 15;
    const int q   = L >> 4;
    const long row0 = (long)blockIdx.x * 64;

    // ---- init ----
    {
        int* hz = (int*)&h_pack[0][0];
        for (int idx = tid; idx < 18432; idx += 512) hz[idx] = 0;  // both bufs
    }
    __syncthreads();
    if (tid < 128) {   // "1" column, both buffers, never overwritten
        int buf = tid >> 6, b = tid & 63;
        h_pack[buf][((b >> 4) * 9 + 8) * 512 + (b & 15) * 8 + 2] = (_Float16)1.f;
    }
    if (tid < 128) {   // x(0) into buf0
        int b = tid >> 1, jj = tid & 1;
        h_pack[0][((b >> 4) * 9 + 8) * 512 + (b & 15) * 8 + jj] =
            (_Float16)x_input[(row0 + b) * 2 + jj];
    }

    const float bo = b_out[tid & 1];
    const int aoff = q * 128 + l16 * 8;
    const _Float16* __restrict__ wenc_w  = &g_w_enc[w * 36864];
    const _Float16* __restrict__ wdec0_w = &g_w_dec0[w * 36864];
    const _Float16* __restrict__ wdeff_w = &g_w_deff[w * 36864];

    _Float16 wo[2][2][4];   // [jj][cc][r] for cells 32w+16cc+4q+r
#pragma unroll
    for (int jj = 0; jj < 2; jj++)
#pragma unroll
        for (int cc = 0; cc < 2; cc++)
#pragma unroll
            for (int r = 0; r < 4; r++)
                wo[jj][cc][r] = g_wout[jj * 256 + 32 * w + 16 * cc + 4 * q + r];

    floatx4 acc[8][4];
    float   c_st[4][2][4];
#pragma unroll
    for (int nt = 0; nt < 4; nt++)
#pragma unroll
        for (int cc = 0; cc < 2; cc++)
#pragma unroll
            for (int r = 0; r < 4; r++) c_st[nt][cc][r] = 0.f;

    __syncthreads();

    int cur = 0;
#pragma unroll 1
    for (int t = 0; t < SEQ + TLEN; t++) {
        const _Float16* __restrict__ Wb =
            (t < SEQ) ? wenc_w : (t == SEQ) ? wdec0_w : wdeff_w;
        const _Float16* __restrict__ hp = h_pack[cur];
        _Float16* __restrict__ hn = h_pack[cur ^ 1];
        const bool dec = (t >= SEQ);

        float xval = 0.f;
        if (t < SEQ && tid < 128) {
            int srct = (t + 1 < SEQ) ? t + 1 : SEQ - 1;
            xval = x_input[(long)srct * 32768 + (row0 + (tid >> 1)) * 2 + (tid & 1)];
        }

        float po[4][2];
#pragma unroll
        for (int nt = 0; nt < 4; nt++) { po[nt][0] = 0.f; po[nt][1] = 0.f; }

        // ==== PassA: gates for cc=0 cells (i=0..3), all kt ====
#pragma unroll
        for (int kt = 0; kt < 9; kt++) {
            half8 B[4];
#pragma unroll
            for (int nt = 0; nt < 4; nt++)
                B[nt] = *(const half8*)&hp[(nt * 9 + kt) * 512 + aoff];
#pragma unroll
            for (int i = 0; i < 4; i++) {
                half8 Aw = *(const half8*)&Wb[(kt * 8 + i) * 512 + aoff];
                if (kt == 0) {
#pragma unroll
                    for (int nt = 0; nt < 4; nt++)
                        acc[i][nt] = __builtin_amdgcn_mfma_f32_16x16x32_f16(
                            Aw, B[nt], (floatx4)(0.f), 0, 0, 0);
                } else {
#pragma unroll
                    for (int nt = 0; nt < 4; nt++)
                        acc[i][nt] = __builtin_amdgcn_mfma_f32_16x16x32_f16(
                            Aw, B[nt], acc[i][nt], 0, 0, 0);
                }
            }
        }

        // ==== E0: elementwise LSTM for cc=0 cells (needs acc[0..3] only).
        // Contiguous block; scheduler sinks it into PassB's MFMA shadow. ====
#pragma unroll
        for (int nt = 0; nt < 4; nt++) {
            const int cc = 0;
            half4 hv4;
            float hvf[4];
#pragma unroll
            for (int r = 0; r < 4; r++) {
                float ai = acc[0][nt][r];
                float af = acc[1][nt][r];
                float ag = acc[2][nt][r];
                float ao = acc[3][nt][r];
                float eI = __builtin_amdgcn_exp2f(-ai);
                float eF = __builtin_amdgcn_exp2f(-af);
                float eG = __builtin_amdgcn_exp2f(-ag);
                float eO = __builtin_amdgcn_exp2f(-ao);
                float a1 = 1.f + eI;
                float a2 = 1.f + eG;
                float a3 = 1.f + eF;
                float t1 = a1 * a2;
                float num = fmaf(c_st[nt][cc][r], t1, (1.f - eG) * a3);
                float cn  = num * __builtin_amdgcn_rcpf(t1 * a3);
                c_st[nt][cc][r] = cn;
                float cnc = fmaxf(cn, -12.f);   // upper clamp unnecessary
                float eC = __builtin_amdgcn_exp2f(-LOG2E2 * cnc);
                float hv = (1.f - eC) *
                    __builtin_amdgcn_rcpf((1.f + eO) * (1.f + eC));
                hvf[r] = hv;
                hv4[r] = (_Float16)hv;
            }
            *(half4*)&hn[(nt * 9 + w) * 512 + (2 * cc + (q >> 1)) * 128 +
                         l16 * 8 + 4 * (q & 1)] = hv4;
            if (dec) {
#pragma unroll
                for (int r = 0; r < 4; r++) {
                    po[nt][0] = fmaf(hvf[r], (float)wo[0][cc][r], po[nt][0]);
                    po[nt][1] = fmaf(hvf[r], (float)wo[1][cc][r], po[nt][1]);
                }
            }
        }

        // ==== PassB: gates for cc=1 cells (i=4..7), all kt ====
#pragma unroll
        for (int kt = 0; kt < 9; kt++) {
            half8 B[4];
#pragma unroll
            for (int nt = 0; nt < 4; nt++)
                B[nt] = *(const half8*)&hp[(nt * 9 + kt) * 512 + aoff];
#pragma unroll
            for (int i = 4; i < 8; i++) {
                half8 Aw = *(const half8*)&Wb[(kt * 8 + i) * 512 + aoff];
                if (kt == 0) {
#pragma unroll
                    for (int nt = 0; nt < 4; nt++)
                        acc[i][nt] = __builtin_amdgcn_mfma_f32_16x16x32_f16(
                            Aw, B[nt], (floatx4)(0.f), 0, 0, 0);
                } else {
#pragma unroll
                    for (int nt = 0; nt < 4; nt++)
                        acc[i][nt] = __builtin_amdgcn_mfma_f32_16x16x32_f16(
                            Aw, B[nt], acc[i][nt], 0, 0, 0);
                }
            }
        }

        // ==== E1: elementwise LSTM for cc=1 cells (acc[4..7]) ====
#pragma unroll
        for (int nt = 0; nt < 4; nt++) {
            const int cc = 1;
            half4 hv4;
            float hvf[4];
#pragma unroll
            for (int r = 0; r < 4; r++) {
                float ai = acc[4][nt][r];
                float af = acc[5][nt][r];
                float ag = acc[6][nt][r];
                float ao = acc[7][nt][r];
                float eI = __builtin_amdgcn_exp2f(-ai);
                float eF = __builtin_amdgcn_exp2f(-af);
                float eG = __builtin_amdgcn_exp2f(-ag);
                float eO = __builtin_amdgcn_exp2f(-ao);
                float a1 = 1.f + eI;
                float a2 = 1.f + eG;
                float a3 = 1.f + eF;
                float t1 = a1 * a2;
                float num = fmaf(c_st[nt][cc][r], t1, (1.f - eG) * a3);
                float cn  = num * __builtin_amdgcn_rcpf(t1 * a3);
                c_st[nt][cc][r] = cn;
                float cnc = fmaxf(cn, -12.f);
                float eC = __builtin_amdgcn_exp2f(-LOG2E2 * cnc);
                float hv = (1.f - eC) *
                    __builtin_amdgcn_rcpf((1.f + eO) * (1.f + eC));
                hvf[r] = hv;
                hv4[r] = (_Float16)hv;
            }
            *(half4*)&hn[(nt * 9 + w) * 512 + (2 * cc + (q >> 1)) * 128 +
                         l16 * 8 + 4 * (q & 1)] = hv4;
            if (dec) {
#pragma unroll
                for (int r = 0; r < 4; r++) {
                    po[nt][0] = fmaf(hvf[r], (float)wo[0][cc][r], po[nt][0]);
                    po[nt][1] = fmaf(hvf[r], (float)wo[1][cc][r], po[nt][1]);
                }
            }
        }

        if (dec) {
#pragma unroll
            for (int nt = 0; nt < 4; nt++)
#pragma unroll
                for (int jj = 0; jj < 2; jj++) {
                    float s = po[nt][jj];
                    s += __shfl_xor(s, 16);
                    s += __shfl_xor(s, 32);
                    po[nt][jj] = s;
                }
            if (q == 0) {
                float* pl = &partial_lds[t & 1][w * 132];
#pragma unroll
                for (int nt = 0; nt < 4; nt++) {
                    pl[nt * 16 + l16]      = po[nt][0];
                    pl[66 + nt * 16 + l16] = po[nt][1];
                }
            }
        }

        if (t < SEQ && tid < 128) {
            int b = tid >> 1, jj = tid & 1;
            hn[((b >> 4) * 9 + 8) * 512 + (b & 15) * 8 + jj] = (_Float16)xval;
        }

        __syncthreads();   // hn + partials complete

        if (dec && tid < 128) {
            int m = tid >> 1, jj = tid & 1;
            const float* pl = &partial_lds[t & 1][jj * 66 + m];
            float s = bo;
#pragma unroll
            for (int w8 = 0; w8 < 8; w8++) s += pl[w8 * 132];
            out[(long)(t - SEQ) * 32768 + (row0 + m) * 2 + jj] = s;
        }

        cur ^= 1;
    }
}

extern "C" void kernel_launch(void* const* d_in, const int* in_sizes, int n_in,
                              void* d_out, int out_size, void* d_ws, size_t ws_size,
                              hipStream_t stream) {
    (void)in_sizes; (void)n_in; (void)d_ws; (void)ws_size; (void)out_size;
    const float* x      = (const float*)d_in[0];
    const float* W_emb  = (const float*)d_in[1];
    const float* b_emb  = (const float*)d_in[2];
    const float* W_ih_e = (const float*)d_in[3];
    const float* W_hh_e = (const float*)d_in[4];
    const float* b_enc  = (const float*)d_in[5];
    const float* W_ih_d = (const float*)d_in[6];
    const float* W_hh_d = (const float*)d_in[7];
    const float* b_dec  = (const float*)d_in[8];
    const float* W_out  = (const float*)d_in[9];
    const float* b_out  = (const float*)d_in[10];
    float* outp = (float*)d_out;

    prep_kernel<<<512, 256, 0, stream>>>(W_emb, b_emb, W_ih_e, W_hh_e, b_enc,
                                         W_ih_d, W_hh_d, b_dec, W_out, b_out);
    lstm_fused<<<256, 512, 0, stream>>>(x, b_out, outp);
}

// Round 10
// 572.895 us; speedup vs baseline: 1.1745x; 1.0285x over previous
//
#include <hip/hip_runtime.h>

// lstm_seq2seq fused persistent kernel for MI355X (gfx950), R18.
// = R14/R17 body (256 WGs x 512 thr x 64 rows, 1 WG/CU; A=weights streamed
// from L2 wave-contiguous; B=h in LDS double-buffer; c-state in regs;
// decoder feedback folded into weights; K=288 augmented, "1" column carries
// bias; log2e folded into weight rows; kt=0 literal-zero C; merged-rcp EW;
// Pass/E split by cc-halves) with ONE change:
//   - WAVE-LEVEL ANTI-PHASE: waves with parity ((w>>2)&1)==0 run
//     Pass(cc0);E0;Pass(cc1);E1 and parity==1 waves run
//     Pass(cc1);E1;Pass(cc0);E0. Waves s and s+4 share a SIMD (round-robin
//     wave->SIMD assignment), so each SIMD hosts one wave of each parity:
//     while one wave is in an EW block (VALU/trans pipe) its SIMD-mate is
//     in an MFMA pass -> sustained M/E pipe overlap at the HW scheduler
//     level, needing NO compiler interleave (R16 failed) and NO extra
//     occupancy (R12 failed). Also halves instantaneous L2 weight-stream
//     demand (half the waves stream at a time; per-XCD L2 was at ceiling
//     during lockstep M-phases).
//     The parity branch is wave-uniform (s_cbranch, no exec divergence);
//     each arm is a verbatim R14 body via template<int> helpers (all
//     acc/c_st indices compile-time; per-arm live ranges identical to R14;
//     acc dead at the join).
// Session ledger (hot us): R8/R11 590 -> R14/R17 552-572. Failed: R15
// 32x32 MFMA 681 (stream-bound); R16 manual interleave 669 (VGPR cap);
// R12 2WG/CU 921 (stream x2 + spill); R9/R13 A-staging 666/721.

#define SEQ  20
#define TLEN 30
#define LOG2E  1.442695041f
#define LOG2E2 2.885390082f

typedef _Float16 half8   __attribute__((ext_vector_type(8)));
typedef _Float16 half4   __attribute__((ext_vector_type(4)));
typedef float    floatx4 __attribute__((ext_vector_type(4)));

// Packed weights. Gate row n (0..1023), k (0..287):
//   g=n>>8, c=(n>>4)&15, l16=n&15, w=c>>1, cc=c&1, i=cc*4+g,
//   kt=k>>5, q=(k>>3)&3, j=k&7
//   dst = ((w*9+kt)*8 + i)*512 + q*128 + l16*8 + j
// => per (wave,kt): 8 contiguous 1KB A-fragments (8KB block).
__device__ _Float16 g_w_enc[1024 * 288];
__device__ _Float16 g_w_dec0[1024 * 288];
__device__ _Float16 g_w_deff[1024 * 288];
__device__ _Float16 g_wout[512];           // W_out [2][256] f16 (unscaled)

__global__ void prep_kernel(const float* __restrict__ W_emb,
                            const float* __restrict__ b_emb,
                            const float* __restrict__ W_ih_enc,
                            const float* __restrict__ W_hh_enc,
                            const float* __restrict__ b_enc,
                            const float* __restrict__ W_ih_dec,
                            const float* __restrict__ W_hh_dec,
                            const float* __restrict__ b_dec,
                            const float* __restrict__ W_out,
                            const float* __restrict__ b_out) {
    int gid = blockIdx.x * blockDim.x + threadIdx.x;
    int stride = gridDim.x * blockDim.x;
    for (int s = gid; s < 1024 * 288; s += stride) {
        int n = s / 288, k = s - n * 288;
        int g = n >> 8, c = (n >> 4) & 15, l16 = n & 15;
        int w = c >> 1, cc = c & 1;
        int i = cc * 4 + g;
        int kt = k >> 5, q = (k >> 3) & 3, j = k & 7;
        int dst = ((w * 9 + kt) * 8 + i) * 512 + q * 128 + l16 * 8 + j;
        float sc = (g == 2) ? LOG2E2 : LOG2E;   // exp2-folded row scale
        float fe = 0.f, fd = 0.f, ff = 0.f;
        if (k < 256) {
            fe = W_hh_enc[n * 256 + k];
            fd = W_hh_dec[n * 256 + k];
            ff = fd + W_ih_dec[2 * n] * W_out[k]
                    + W_ih_dec[2 * n + 1] * W_out[256 + k];
        } else {
            int kp = k - 256;
            if (kp < 2) {
                fd = W_ih_dec[2 * n + kp];
                const float* wr = &W_ih_enc[n * 64];
                for (int e = 0; e < 64; e++) fe = fmaf(wr[e], W_emb[2 * e + kp], fe);
            } else if (kp == 2) {
                fd = b_dec[n];
                ff = b_dec[n] + W_ih_dec[2 * n] * b_out[0]
                              + W_ih_dec[2 * n + 1] * b_out[1];
                fe = b_enc[n];
                const float* wr = &W_ih_enc[n * 64];
                for (int e = 0; e < 64; e++) fe = fmaf(wr[e], b_emb[e], fe);
            }
        }
        g_w_enc[dst]  = (_Float16)(fe * sc);
        g_w_dec0[dst] = (_Float16)(fd * sc);
        g_w_deff[dst] = (_Float16)(ff * sc);
    }
    if (gid < 512) g_wout[gid] = (_Float16)W_out[gid];
}

// MFMA half-pass: gates i = I0..I0+3 (cells cc = I0/4), all kt.
template<int I0>
__device__ __forceinline__ void mfma_pass(
        const _Float16* __restrict__ Wb,
        const _Float16* __restrict__ hp,
        int aoff, floatx4 (&acc)[8][4])
{
#pragma unroll
    for (int kt = 0; kt < 9; kt++) {
        half8 B[4];
#pragma unroll
        for (int nt = 0; nt < 4; nt++)
            B[nt] = *(const half8*)&hp[(nt * 9 + kt) * 512 + aoff];
#pragma unroll
        for (int ii = 0; ii < 4; ii++) {
            const int i = I0 + ii;
            half8 Aw = *(const half8*)&Wb[(kt * 8 + i) * 512 + aoff];
            if (kt == 0) {
#pragma unroll
                for (int nt = 0; nt < 4; nt++)
                    acc[i][nt] = __builtin_amdgcn_mfma_f32_16x16x32_f16(
                        Aw, B[nt], (floatx4)(0.f), 0, 0, 0);
            } else {
#pragma unroll
                for (int nt = 0; nt < 4; nt++)
                    acc[i][nt] = __builtin_amdgcn_mfma_f32_16x16x32_f16(
                        Aw, B[nt], acc[i][nt], 0, 0, 0);
            }
        }
    }
}

// EW half: merged-rcp LSTM elementwise for cells of parity CC
// (reads acc[CC*4 .. CC*4+3]), h-store, decoder po accumulation.
template<int CC>
__device__ __forceinline__ void ew_half(
        floatx4 (&acc)[8][4], float (&c_st)[4][2][4],
        float (&po)[4][2], const _Float16 (&wo)[2][2][4],
        _Float16* __restrict__ hn, bool dec,
        int w, int q, int l16)
{
#pragma unroll
    for (int nt = 0; nt < 4; nt++) {
        half4 hv4;
        float hvf[4];
#pragma unroll
        for (int r = 0; r < 4; r++) {
            float ai = acc[CC * 4 + 0][nt][r];
            float af = acc[CC * 4 + 1][nt][r];
            float ag = acc[CC * 4 + 2][nt][r];
            float ao = acc[CC * 4 + 3][nt][r];
            float eI = __builtin_amdgcn_exp2f(-ai);
            float eF = __builtin_amdgcn_exp2f(-af);
            float eG = __builtin_amdgcn_exp2f(-ag);
            float eO = __builtin_amdgcn_exp2f(-ao);
            float a1 = 1.f + eI;
            float a2 = 1.f + eG;
            float a3 = 1.f + eF;
            float t1 = a1 * a2;
            float num = fmaf(c_st[nt][CC][r], t1, (1.f - eG) * a3);
            float cn  = num * __builtin_amdgcn_rcpf(t1 * a3);
            c_st[nt][CC][r] = cn;
            float cnc = fmaxf(cn, -12.f);   // upper clamp unnecessary
            float eC = __builtin_amdgcn_exp2f(-LOG2E2 * cnc);
            float hv = (1.f - eC) *
                __builtin_amdgcn_rcpf((1.f + eO) * (1.f + eC));
            hvf[r] = hv;
            hv4[r] = (_Float16)hv;
        }
        *(half4*)&hn[(nt * 9 + w) * 512 + (2 * CC + (q >> 1)) * 128 +
                     l16 * 8 + 4 * (q & 1)] = hv4;
        if (dec) {
#pragma unroll
            for (int r = 0; r < 4; r++) {
                po[nt][0] = fmaf(hvf[r], (float)wo[0][CC][r], po[nt][0]);
                po[nt][1] = fmaf(hvf[r], (float)wo[1][CC][r], po[nt][1]);
            }
        }
    }
}

__global__ __launch_bounds__(512, 2) void lstm_fused(
        const float* __restrict__ x_input,    // [20][16384][2]
        const float* __restrict__ b_out,      // [2]
        float* __restrict__ out)              // [30][16384][2]
{
    __shared__ __align__(16) _Float16 h_pack[2][18432];        // 73728 B
    __shared__ __align__(16) float    partial_lds[2][8 * 132]; // 8448 B

    const int tid = threadIdx.x;
    const int w   = tid >> 6;
    const int L   = tid & 63;
    const int l16 = L & 15;
    const int q   = L >> 4;
    const long row0 = (long)blockIdx.x * 64;
    // waves s and s+4 share a SIMD (round-robin) -> anti-phase parity:
    const bool par = ((w >> 2) & 1) != 0;

    // ---- init ----
    {
        int* hz = (int*)&h_pack[0][0];
        for (int idx = tid; idx < 18432; idx += 512) hz[idx] = 0;  // both bufs
    }
    __syncthreads();
    if (tid < 128) {   // "1" column, both buffers, never overwritten
        int buf = tid >> 6, b = tid & 63;
        h_pack[buf][((b >> 4) * 9 + 8) * 512 + (b & 15) * 8 + 2] = (_Float16)1.f;
    }
    if (tid < 128) {   // x(0) into buf0
        int b = tid >> 1, jj = tid & 1;
        h_pack[0][((b >> 4) * 9 + 8) * 512 + (b & 15) * 8 + jj] =
            (_Float16)x_input[(row0 + b) * 2 + jj];
    }

    const float bo = b_out[tid & 1];
    const int aoff = q * 128 + l16 * 8;
    const _Float16* __restrict__ wenc_w  = &g_w_enc[w * 36864];
    const _Float16* __restrict__ wdec0_w = &g_w_dec0[w * 36864];
    const _Float16* __restrict__ wdeff_w = &g_w_deff[w * 36864];

    _Float16 wo[2][2][4];   // [jj][cc][r] for cells 32w+16cc+4q+r
#pragma unroll
    for (int jj = 0; jj < 2; jj++)
#pragma unroll
        for (int cc = 0; cc < 2; cc++)
#pragma unroll
            for (int r = 0; r < 4; r++)
                wo[jj][cc][r] = g_wout[jj * 256 + 32 * w + 16 * cc + 4 * q + r];

    floatx4 acc[8][4];
    float   c_st[4][2][4];
#pragma unroll
    for (int nt = 0; nt < 4; nt++)
#pragma unroll
        for (int cc = 0; cc < 2; cc++)
#pragma unroll
            for (int r = 0; r < 4; r++) c_st[nt][cc][r] = 0.f;

    __syncthreads();

    int cur = 0;
#pragma unroll 1
    for (int t = 0; t < SEQ + TLEN; t++) {
        const _Float16* __restrict__ Wb =
            (t < SEQ) ? wenc_w : (t == SEQ) ? wdec0_w : wdeff_w;
        const _Float16* __restrict__ hp = h_pack[cur];
        _Float16* __restrict__ hn = h_pack[cur ^ 1];
        const bool dec = (t >= SEQ);

        float xval = 0.f;
        if (t < SEQ && tid < 128) {
            int srct = (t + 1 < SEQ) ? t + 1 : SEQ - 1;
            xval = x_input[(long)srct * 32768 + (row0 + (tid >> 1)) * 2 + (tid & 1)];
        }

        float po[4][2];
#pragma unroll
        for (int nt = 0; nt < 4; nt++) { po[nt][0] = 0.f; po[nt][1] = 0.f; }

        // ==== anti-phase pass/EW sequence (wave-uniform branch) ====
        if (!par) {
            mfma_pass<0>(Wb, hp, aoff, acc);
            ew_half<0>(acc, c_st, po, wo, hn, dec, w, q, l16);
            mfma_pass<4>(Wb, hp, aoff, acc);
            ew_half<1>(acc, c_st, po, wo, hn, dec, w, q, l16);
        } else {
            mfma_pass<4>(Wb, hp, aoff, acc);
            ew_half<1>(acc, c_st, po, wo, hn, dec, w, q, l16);
            mfma_pass<0>(Wb, hp, aoff, acc);
            ew_half<0>(acc, c_st, po, wo, hn, dec, w, q, l16);
        }

        if (dec) {
#pragma unroll
            for (int nt = 0; nt < 4; nt++)
#pragma unroll
                for (int jj = 0; jj < 2; jj++) {
                    float s = po[nt][jj];
                    s += __shfl_xor(s, 16);
                    s += __shfl_xor(s, 32);
                    po[nt][jj] = s;
                }
            if (q == 0) {
                float* pl = &partial_lds[t & 1][w * 132];
#pragma unroll
                for (int nt = 0; nt < 4; nt++) {
                    pl[nt * 16 + l16]      = po[nt][0];
                    pl[66 + nt * 16 + l16] = po[nt][1];
                }
            }
        }

        if (t < SEQ && tid < 128) {
            int b = tid >> 1, jj = tid & 1;
            hn[((b >> 4) * 9 + 8) * 512 + (b & 15) * 8 + jj] = (_Float16)xval;
        }

        __syncthreads();   // hn + partials complete

        if (dec && tid < 128) {
            int m = tid >> 1, jj = tid & 1;
            const float* pl = &partial_lds[t & 1][jj * 66 + m];
            float s = bo;
#pragma unroll
            for (int w8 = 0; w8 < 8; w8++) s += pl[w8 * 132];
            out[(long)(t - SEQ) * 32768 + (row0 + m) * 2 + jj] = s;
        }

        cur ^= 1;
    }
}

extern "C" void kernel_launch(void* const* d_in, const int* in_sizes, int n_in,
                              void* d_out, int out_size, void* d_ws, size_t ws_size,
                              hipStream_t stream) {
    (void)in_sizes; (void)n_in; (void)d_ws; (void)ws_size; (void)out_size;
    const float* x      = (const float*)d_in[0];
    const float* W_emb  = (const float*)d_in[1];
    const float* b_emb  = (const float*)d_in[2];
    const float* W_ih_e = (const float*)d_in[3];
    const float* W_hh_e = (const float*)d_in[4];
    const float* b_enc  = (const float*)d_in[5];
    const float* W_ih_d = (const float*)d_in[6];
    const float* W_hh_d = (const float*)d_in[7];
    const float* b_dec  = (const float*)d_in[8];
    const float* W_out  = (const float*)d_in[9];
    const float* b_out  = (const float*)d_in[10];
    float* outp = (float*)d_out;

    prep_kernel<<<512, 256, 0, stream>>>(W_emb, b_emb, W_ih_e, W_hh_e, b_enc,
                                         W_ih_d, W_hh_d, b_dec, W_out, b_out);
    lstm_fused<<<256, 512, 0, stream>>>(x, b_out, outp);
}